// Round 4
// baseline (74.766 us; speedup 1.0000x reference)
//
#include <hip/hip_runtime.h>

// SimpleGNN: B=4, N=512, D=128, L=2
// Algebraic rewrite: sum over j commutes with the (linear) second layer:
//   msg[b,i,:] = (sum_j adj[b,i,j]*relu(ai'[b,i,:]+aj[b,j,:])) @ w2^T
//              + (sum_j adj[b,i,j]) * b2
// where ai' = h @ wi^T + b1, aj = h @ wj^T.
// msg kernel v3: aj tile staged ONCE in LDS (no inner barriers, no double
// buffer); adj operand fetched via wave-uniform addresses -> SMEM (s_load),
// so the inner loop is ~98% VALU. TI=16 rows/block amortizes every LDS read
// over 48 VALU ops.

constexpr int Bc = 4, Nc = 512, Dc = 128, Lc = 2;
constexpr int BN = Bc * Nc;  // 2048
constexpr int TI = 16;       // i-rows per msg block
constexpr int JS = 8;        // j-split factor (partial sums)
constexpr int JT = Nc / JS;  // 64 j's per block
constexpr int JH = JT / 2;   // 32 j's per half
constexpr int TN = 4;        // rows per lin block

// --- weight transpose: wiT[l][d][o] = w1[l][o][d], wjT[l][d][o] = w1[l][o][D+d],
//                       w2T[l][d][o] = w2[l][o][d]
__global__ void transpose_w_kernel(const float* __restrict__ w1,
                                   const float* __restrict__ w2,
                                   float* __restrict__ wiT,
                                   float* __restrict__ wjT,
                                   float* __restrict__ w2T) {
    int idx = blockIdx.x * blockDim.x + threadIdx.x;
    if (idx >= Lc * Dc * Dc) return;
    int l = idx / (Dc * Dc);
    int rem = idx - l * Dc * Dc;
    int d = rem / Dc;
    int o = rem - d * Dc;
    wiT[idx] = w1[(l * Dc + o) * (2 * Dc) + d];
    wjT[idx] = w1[(l * Dc + o) * (2 * Dc) + Dc + d];
    w2T[idx] = w2[(l * Dc + o) * Dc + d];
}

// --- masked-relu reduction over a j-range (partial over js):
//   sp[js][r][d] = sum_{j in range} adj[b,i,j] * relu(ai'[r][d] + aj[b,j,d])
//   arowp[js][r] = sum_{j in range} adj[b,i,j]
__global__ __launch_bounds__(256) void gnn_msg(const float* __restrict__ ai,
                                               const float* __restrict__ aj,
                                               const float* __restrict__ adj,
                                               float* __restrict__ sp,
                                               float* __restrict__ arowp) {
    __shared__ __align__(16) float ajs[JT][Dc];  // 32 KB, staged once

    const int tid = threadIdx.x;
    const int d = tid & 127;
    const int half = tid >> 7;
    const int js = blockIdx.x & (JS - 1);
    const int rblk = blockIdx.x >> 3;  // JS==8
    const int r0 = rblk * TI;
    const int b = r0 / Nc;
    const int i0 = r0 - b * Nc;
    const int j0 = js * JT;
    const int j0h = j0 + half * JH;
    const float* __restrict__ ajb = aj + (size_t)b * Nc * Dc;
    const float* __restrict__ adjb = adj + (size_t)b * Nc * Nc;

    // ---- stage full aj tile [j0, j0+JT) x [0,Dc): 8 float4 per thread
    {
        const int jr = tid >> 5;          // 0..7
        const int c4 = (tid & 31) << 2;   // 0..124
        float4 tmp[8];
#pragma unroll
        for (int q = 0; q < 8; ++q)
            tmp[q] = *reinterpret_cast<const float4*>(
                &ajb[(size_t)(j0 + jr + q * 8) * Dc + c4]);
#pragma unroll
        for (int q = 0; q < 8; ++q)
            *reinterpret_cast<float4*>(&ajs[jr + q * 8][c4]) = tmp[q];
    }

    // ---- arow partials: 16 threads per row, shfl-reduce within 16-lane group
    {
        const int rr = tid >> 4;  // 0..15
        const int k = tid & 15;
        const float4 av = *reinterpret_cast<const float4*>(
            &adjb[(size_t)(i0 + rr) * Nc + j0 + k * 4]);
        float pssum = av.x + av.y + av.z + av.w;
#pragma unroll
        for (int m = 8; m >= 1; m >>= 1) pssum += __shfl_xor(pssum, m);
        if (k == 0) arowp[js * BN + r0 + rr] = pssum;
    }

    float x[TI], acc[TI];
#pragma unroll
    for (int r = 0; r < TI; ++r) {
        x[r] = ai[(size_t)(r0 + r) * Dc + d];
        acc[r] = 0.f;
    }
    __syncthreads();

    // ---- inner loop: no barriers; v from LDS, adj via uniform (SMEM) loads
    const float* __restrict__ adjrow0 = adjb + (size_t)i0 * Nc + j0h;
    for (int g = 0; g < JH; g += 8) {
        float v[8];
#pragma unroll
        for (int k = 0; k < 8; ++k) v[k] = ajs[half * JH + g + k][d];
#pragma unroll
        for (int r = 0; r < TI; ++r) {
            const float* __restrict__ arw = adjrow0 + (size_t)r * Nc + g;
#pragma unroll
            for (int k = 0; k < 8; ++k)
                acc[r] = fmaf(arw[k], fmaxf(x[r] + v[k], 0.f), acc[r]);
        }
    }

    // ---- combine halves (reuse ajs as accred[TI][Dc])
    __syncthreads();
    float* accred = &ajs[0][0];
    if (half == 1) {
#pragma unroll
        for (int r = 0; r < TI; ++r) accred[r * Dc + d] = acc[r];
    }
    __syncthreads();
    if (half == 0) {
#pragma unroll
        for (int r = 0; r < TI; ++r)
            sp[((size_t)js * BN + r0 + r) * Dc + d] = acc[r] + accred[r * Dc + d];
    }
}

// --- first linear, d-split across 2 half-blocks + ping-pong weight prefetch
__global__ __launch_bounds__(256) void gnn_lin1(const float* __restrict__ h,
                                                const float* __restrict__ wiT,
                                                const float* __restrict__ wjT,
                                                const float* __restrict__ b1,
                                                float* __restrict__ ai,
                                                float* __restrict__ aj) {
    __shared__ __align__(16) float hs[TN][Dc];
    __shared__ float redi[TN][Dc], redj[TN][Dc];
    const int tid = threadIdx.x;
    const int o = tid & 127;
    const int hh = tid >> 7;
    const int r0 = blockIdx.x * TN;
#pragma unroll
    for (int rep = 0; rep < 2; ++rep) {
        const int lin = rep * 256 + tid;
        hs[lin >> 7][lin & 127] = h[(size_t)(r0 + (lin >> 7)) * Dc + (lin & 127)];
    }
    __syncthreads();
    float acci[TN] = {}, accj[TN] = {};
    const int db = hh * 64;
    float wiA[4], wjA[4], wiB[4], wjB[4];
    for (int k = 0; k < 4; ++k) {
        wiA[k] = wiT[(size_t)(db + k) * Dc + o];
        wjA[k] = wjT[(size_t)(db + k) * Dc + o];
    }
    for (int dd = 0; dd < 64; dd += 8) {
        for (int k = 0; k < 4; ++k) {
            wiB[k] = wiT[(size_t)(db + dd + 4 + k) * Dc + o];
            wjB[k] = wjT[(size_t)(db + dd + 4 + k) * Dc + o];
        }
#pragma unroll
        for (int t = 0; t < TN; ++t) {
            const float4 hv = *reinterpret_cast<const float4*>(&hs[t][db + dd]);
            acci[t] = fmaf(hv.x, wiA[0], acci[t]); acci[t] = fmaf(hv.y, wiA[1], acci[t]);
            acci[t] = fmaf(hv.z, wiA[2], acci[t]); acci[t] = fmaf(hv.w, wiA[3], acci[t]);
            accj[t] = fmaf(hv.x, wjA[0], accj[t]); accj[t] = fmaf(hv.y, wjA[1], accj[t]);
            accj[t] = fmaf(hv.z, wjA[2], accj[t]); accj[t] = fmaf(hv.w, wjA[3], accj[t]);
        }
        if (dd + 8 < 64) {
            for (int k = 0; k < 4; ++k) {
                wiA[k] = wiT[(size_t)(db + dd + 8 + k) * Dc + o];
                wjA[k] = wjT[(size_t)(db + dd + 8 + k) * Dc + o];
            }
        }
#pragma unroll
        for (int t = 0; t < TN; ++t) {
            const float4 hv = *reinterpret_cast<const float4*>(&hs[t][db + dd + 4]);
            acci[t] = fmaf(hv.x, wiB[0], acci[t]); acci[t] = fmaf(hv.y, wiB[1], acci[t]);
            acci[t] = fmaf(hv.z, wiB[2], acci[t]); acci[t] = fmaf(hv.w, wiB[3], acci[t]);
            accj[t] = fmaf(hv.x, wjB[0], accj[t]); accj[t] = fmaf(hv.y, wjB[1], accj[t]);
            accj[t] = fmaf(hv.z, wjB[2], accj[t]); accj[t] = fmaf(hv.w, wjB[3], accj[t]);
        }
    }
    if (hh == 1) {
#pragma unroll
        for (int t = 0; t < TN; ++t) { redi[t][o] = acci[t]; redj[t][o] = accj[t]; }
    }
    __syncthreads();
    if (hh == 0) {
        const float bo = b1[o];
#pragma unroll
        for (int t = 0; t < TN; ++t) {
            ai[(size_t)(r0 + t) * Dc + o] = acci[t] + redi[t][o] + bo;
            aj[(size_t)(r0 + t) * Dc + o] = accj[t] + redj[t][o];
        }
    }
}

// --- final second linear + residual (sums JS partials), d-split
__global__ __launch_bounds__(256) void gnn_lin2(const float* __restrict__ hin,
                                                const float* __restrict__ sp,
                                                const float* __restrict__ arowp,
                                                const float* __restrict__ w2T,
                                                const float* __restrict__ b2,
                                                float* __restrict__ hout) {
    __shared__ __align__(16) float ss[TN][Dc];
    __shared__ float red[TN][Dc];
    __shared__ float arsh[TN];
    const int tid = threadIdx.x;
    const int o = tid & 127;
    const int hh = tid >> 7;
    const int r0 = blockIdx.x * TN;
#pragma unroll
    for (int rep = 0; rep < 2; ++rep) {
        const int lin = rep * 256 + tid;
        const int t = lin >> 7, dd = lin & 127;
        float s = 0.f;
#pragma unroll
        for (int j = 0; j < JS; ++j) s += sp[((size_t)j * BN + r0 + t) * Dc + dd];
        ss[t][dd] = s;
    }
    if (tid < TN) {
        float s = 0.f;
        for (int j = 0; j < JS; ++j) s += arowp[j * BN + r0 + tid];
        arsh[tid] = s;
    }
    __syncthreads();
    float acc[TN] = {};
    const int db = hh * 64;
    float wA[4], wB[4];
    for (int k = 0; k < 4; ++k) wA[k] = w2T[(size_t)(db + k) * Dc + o];
    for (int dd = 0; dd < 64; dd += 8) {
        for (int k = 0; k < 4; ++k) wB[k] = w2T[(size_t)(db + dd + 4 + k) * Dc + o];
#pragma unroll
        for (int t = 0; t < TN; ++t) {
            const float4 sv = *reinterpret_cast<const float4*>(&ss[t][db + dd]);
            acc[t] = fmaf(sv.x, wA[0], acc[t]); acc[t] = fmaf(sv.y, wA[1], acc[t]);
            acc[t] = fmaf(sv.z, wA[2], acc[t]); acc[t] = fmaf(sv.w, wA[3], acc[t]);
        }
        if (dd + 8 < 64)
            for (int k = 0; k < 4; ++k) wA[k] = w2T[(size_t)(db + dd + 8 + k) * Dc + o];
#pragma unroll
        for (int t = 0; t < TN; ++t) {
            const float4 sv = *reinterpret_cast<const float4*>(&ss[t][db + dd + 4]);
            acc[t] = fmaf(sv.x, wB[0], acc[t]); acc[t] = fmaf(sv.y, wB[1], acc[t]);
            acc[t] = fmaf(sv.z, wB[2], acc[t]); acc[t] = fmaf(sv.w, wB[3], acc[t]);
        }
    }
    if (hh == 1) {
#pragma unroll
        for (int t = 0; t < TN; ++t) red[t][o] = acc[t];
    }
    __syncthreads();
    if (hh == 0) {
        const float b2o = b2[o];
#pragma unroll
        for (int t = 0; t < TN; ++t)
            hout[(size_t)(r0 + t) * Dc + o] =
                hin[(size_t)(r0 + t) * Dc + o] + acc[t] + red[t][o] + arsh[t] * b2o;
    }
}

// --- fused: lin2 of layer l + residual, then lin1 of layer l+1 (both d-split)
__global__ __launch_bounds__(256) void gnn_lin2lin1(const float* __restrict__ hin,
                                                    const float* __restrict__ sp,
                                                    const float* __restrict__ arowp,
                                                    const float* __restrict__ w2T,
                                                    const float* __restrict__ b2,
                                                    const float* __restrict__ wiT,
                                                    const float* __restrict__ wjT,
                                                    const float* __restrict__ b1,
                                                    float* __restrict__ hout,
                                                    float* __restrict__ ai,
                                                    float* __restrict__ aj) {
    __shared__ __align__(16) float ss[TN][Dc];
    __shared__ float redi[TN][Dc], redj[TN][Dc];
    __shared__ float arsh[TN];
    const int tid = threadIdx.x;
    const int o = tid & 127;
    const int hh = tid >> 7;
    const int r0 = blockIdx.x * TN;
#pragma unroll
    for (int rep = 0; rep < 2; ++rep) {
        const int lin = rep * 256 + tid;
        const int t = lin >> 7, dd = lin & 127;
        float s = 0.f;
#pragma unroll
        for (int j = 0; j < JS; ++j) s += sp[((size_t)j * BN + r0 + t) * Dc + dd];
        ss[t][dd] = s;
    }
    if (tid < TN) {
        float s = 0.f;
        for (int j = 0; j < JS; ++j) s += arowp[j * BN + r0 + tid];
        arsh[tid] = s;
    }
    __syncthreads();
    // ---- stage 1: w2 GEMV
    float acc[TN] = {};
    const int db = hh * 64;
    {
        float wA[4], wB[4];
        for (int k = 0; k < 4; ++k) wA[k] = w2T[(size_t)(db + k) * Dc + o];
        for (int dd = 0; dd < 64; dd += 8) {
            for (int k = 0; k < 4; ++k) wB[k] = w2T[(size_t)(db + dd + 4 + k) * Dc + o];
#pragma unroll
            for (int t = 0; t < TN; ++t) {
                const float4 sv = *reinterpret_cast<const float4*>(&ss[t][db + dd]);
                acc[t] = fmaf(sv.x, wA[0], acc[t]); acc[t] = fmaf(sv.y, wA[1], acc[t]);
                acc[t] = fmaf(sv.z, wA[2], acc[t]); acc[t] = fmaf(sv.w, wA[3], acc[t]);
            }
            if (dd + 8 < 64)
                for (int k = 0; k < 4; ++k) wA[k] = w2T[(size_t)(db + dd + 8 + k) * Dc + o];
#pragma unroll
            for (int t = 0; t < TN; ++t) {
                const float4 sv = *reinterpret_cast<const float4*>(&ss[t][db + dd + 4]);
                acc[t] = fmaf(sv.x, wB[0], acc[t]); acc[t] = fmaf(sv.y, wB[1], acc[t]);
                acc[t] = fmaf(sv.z, wB[2], acc[t]); acc[t] = fmaf(sv.w, wB[3], acc[t]);
            }
        }
    }
    if (hh == 1) {
#pragma unroll
        for (int t = 0; t < TN; ++t) redi[t][o] = acc[t];
    }
    __syncthreads();  // redi ready; ss dead
    if (hh == 0) {
        const float b2o = b2[o];
#pragma unroll
        for (int t = 0; t < TN; ++t) {
            const float hn =
                hin[(size_t)(r0 + t) * Dc + o] + acc[t] + redi[t][o] + arsh[t] * b2o;
            hout[(size_t)(r0 + t) * Dc + o] = hn;
            ss[t][o] = hn;  // restage for stage 2
        }
    }
    __syncthreads();
    // ---- stage 2: lin1 of next layer on ss
    float acci[TN] = {}, accj[TN] = {};
    {
        float wiA[4], wjA[4], wiB[4], wjB[4];
        for (int k = 0; k < 4; ++k) {
            wiA[k] = wiT[(size_t)(db + k) * Dc + o];
            wjA[k] = wjT[(size_t)(db + k) * Dc + o];
        }
        for (int dd = 0; dd < 64; dd += 8) {
            for (int k = 0; k < 4; ++k) {
                wiB[k] = wiT[(size_t)(db + dd + 4 + k) * Dc + o];
                wjB[k] = wjT[(size_t)(db + dd + 4 + k) * Dc + o];
            }
#pragma unroll
            for (int t = 0; t < TN; ++t) {
                const float4 hv = *reinterpret_cast<const float4*>(&ss[t][db + dd]);
                acci[t] = fmaf(hv.x, wiA[0], acci[t]); acci[t] = fmaf(hv.y, wiA[1], acci[t]);
                acci[t] = fmaf(hv.z, wiA[2], acci[t]); acci[t] = fmaf(hv.w, wiA[3], acci[t]);
                accj[t] = fmaf(hv.x, wjA[0], accj[t]); accj[t] = fmaf(hv.y, wjA[1], accj[t]);
                accj[t] = fmaf(hv.z, wjA[2], accj[t]); accj[t] = fmaf(hv.w, wjA[3], accj[t]);
            }
            if (dd + 8 < 64) {
                for (int k = 0; k < 4; ++k) {
                    wiA[k] = wiT[(size_t)(db + dd + 8 + k) * Dc + o];
                    wjA[k] = wjT[(size_t)(db + dd + 8 + k) * Dc + o];
                }
            }
#pragma unroll
            for (int t = 0; t < TN; ++t) {
                const float4 hv = *reinterpret_cast<const float4*>(&ss[t][db + dd + 4]);
                acci[t] = fmaf(hv.x, wiB[0], acci[t]); acci[t] = fmaf(hv.y, wiB[1], acci[t]);
                acci[t] = fmaf(hv.z, wiB[2], acci[t]); acci[t] = fmaf(hv.w, wiB[3], acci[t]);
                accj[t] = fmaf(hv.x, wjB[0], accj[t]); accj[t] = fmaf(hv.y, wjB[1], accj[t]);
                accj[t] = fmaf(hv.z, wjB[2], accj[t]); accj[t] = fmaf(hv.w, wjB[3], accj[t]);
            }
        }
    }
    if (hh == 1) {
#pragma unroll
        for (int t = 0; t < TN; ++t) { redi[t][o] = acci[t]; redj[t][o] = accj[t]; }
    }
    __syncthreads();
    if (hh == 0) {
        const float bo = b1[o];
#pragma unroll
        for (int t = 0; t < TN; ++t) {
            ai[(size_t)(r0 + t) * Dc + o] = acci[t] + redi[t][o] + bo;
            aj[(size_t)(r0 + t) * Dc + o] = accj[t] + redj[t][o];
        }
    }
}

extern "C" void kernel_launch(void* const* d_in, const int* in_sizes, int n_in,
                              void* d_out, int out_size, void* d_ws, size_t ws_size,
                              hipStream_t stream) {
    const float* node = (const float*)d_in[0];
    const float* adj  = (const float*)d_in[1];
    const float* w1   = (const float*)d_in[2];
    const float* b1   = (const float*)d_in[3];
    const float* w2   = (const float*)d_in[4];
    const float* b2   = (const float*)d_in[5];
    float* out = (float*)d_out;

    float* ws = (float*)d_ws;
    float* wiT  = ws; ws += Lc * Dc * Dc;
    float* wjT  = ws; ws += Lc * Dc * Dc;
    float* w2T  = ws; ws += Lc * Dc * Dc;
    float* ai   = ws; ws += BN * Dc;
    float* aj   = ws; ws += BN * Dc;
    float* sp   = ws; ws += (size_t)JS * BN * Dc;
    float* arowp= ws; ws += JS * BN;
    float* h1   = ws; ws += BN * Dc;

    transpose_w_kernel<<<(Lc * Dc * Dc + 255) / 256, 256, 0, stream>>>(w1, w2, wiT, wjT, w2T);

    // layer 0
    gnn_lin1<<<BN / TN, 256, 0, stream>>>(node, wiT, wjT, b1, ai, aj);
    gnn_msg<<<(BN / TI) * JS, 256, 0, stream>>>(ai, aj, adj, sp, arowp);
    gnn_lin2lin1<<<BN / TN, 256, 0, stream>>>(node, sp, arowp, w2T, b2,
                                              wiT + Dc * Dc, wjT + Dc * Dc, b1 + Dc,
                                              h1, ai, aj);
    // layer 1
    gnn_msg<<<(BN / TI) * JS, 256, 0, stream>>>(ai, aj, adj, sp, arowp);
    gnn_lin2<<<BN / TN, 256, 0, stream>>>(h1, sp, arowp, w2T + Dc * Dc, b2 + Dc, out);
}

// Round 5
// 73.245 us; speedup vs baseline: 1.0208x; 1.0208x over previous
//
#include <hip/hip_runtime.h>

// SimpleGNN: B=4, N=512, D=128, L=2
// Algebraic rewrite: sum over j commutes with the (linear) second layer:
//   msg[b,i,:] = (sum_j adj[b,i,j]*relu(ai'[b,i,:]+aj[b,j,:])) @ w2^T
//              + (sum_j adj[b,i,j]) * b2
// where ai' = h @ wi^T + b1, aj = h @ wj^T.
// msg v4: aj tile AND transposed adj slice staged ONCE in LDS; inner loop has
// ZERO barriers and reads only LDS (1 b32 + 4 broadcast b128 per jj feeding
// 48 VALU ops). 3 barriers per block total (vs ~10 in v2).

constexpr int Bc = 4, Nc = 512, Dc = 128, Lc = 2;
constexpr int BN = Bc * Nc;  // 2048
constexpr int TI = 16;       // i-rows per msg block
constexpr int JS = 8;        // j-split factor (partial sums)
constexpr int JT = Nc / JS;  // 64 j's per block
constexpr int JH = JT / 2;   // 32 j's per half
constexpr int TN = 4;        // rows per lin block

// --- weight transpose
__global__ void transpose_w_kernel(const float* __restrict__ w1,
                                   const float* __restrict__ w2,
                                   float* __restrict__ wiT,
                                   float* __restrict__ wjT,
                                   float* __restrict__ w2T) {
    int idx = blockIdx.x * blockDim.x + threadIdx.x;
    if (idx >= Lc * Dc * Dc) return;
    int l = idx / (Dc * Dc);
    int rem = idx - l * Dc * Dc;
    int d = rem / Dc;
    int o = rem - d * Dc;
    wiT[idx] = w1[(l * Dc + o) * (2 * Dc) + d];
    wjT[idx] = w1[(l * Dc + o) * (2 * Dc) + Dc + d];
    w2T[idx] = w2[(l * Dc + o) * Dc + d];
}

// --- masked-relu reduction over a j-range (partial over js):
//   sp[js][r][d] = sum_{j in range} adj[b,i,j] * relu(ai'[r][d] + aj[b,j,d])
//   arowp[js][r] = sum_{j in range} adj[b,i,j]
__global__ __launch_bounds__(256) void gnn_msg(const float* __restrict__ ai,
                                               const float* __restrict__ aj,
                                               const float* __restrict__ adj,
                                               float* __restrict__ sp,
                                               float* __restrict__ arowp) {
    __shared__ __align__(16) float ajs[JT][Dc];    // 32 KB, staged once
    __shared__ __align__(16) float adjsT[JT][TI];  // 4 KB, staged once

    const int tid = threadIdx.x;
    const int d = tid & 127;
    const int half = tid >> 7;
    const int js = blockIdx.x & (JS - 1);
    const int rblk = blockIdx.x >> 3;  // JS==8
    const int r0 = rblk * TI;
    const int b = r0 / Nc;
    const int i0 = r0 - b * Nc;
    const int j0 = js * JT;
    const float* __restrict__ ajb = aj + (size_t)b * Nc * Dc;
    const float* __restrict__ adjb = adj + (size_t)b * Nc * Nc;

    // ---- stage aj tile [j0, j0+JT) x [0,Dc): 8 float4 per thread
    {
        const int jr = tid >> 5;          // 0..7
        const int c4 = (tid & 31) << 2;   // 0..124
        float4 tmp[8];
#pragma unroll
        for (int q = 0; q < 8; ++q)
            tmp[q] = *reinterpret_cast<const float4*>(
                &ajb[(size_t)(j0 + jr + q * 8) * Dc + c4]);
#pragma unroll
        for (int q = 0; q < 8; ++q)
            *reinterpret_cast<float4*>(&ajs[jr + q * 8][c4]) = tmp[q];
    }

    // ---- stage adj slice (transposed) + arow partials
    {
        const int rr = tid >> 4;  // 0..15
        const int k = tid & 15;   // 0..15
        const float4 av = *reinterpret_cast<const float4*>(
            &adjb[(size_t)(i0 + rr) * Nc + j0 + k * 4]);
        adjsT[k * 4 + 0][rr] = av.x;
        adjsT[k * 4 + 1][rr] = av.y;
        adjsT[k * 4 + 2][rr] = av.z;
        adjsT[k * 4 + 3][rr] = av.w;
        float ps = av.x + av.y + av.z + av.w;
#pragma unroll
        for (int m = 8; m >= 1; m >>= 1) ps += __shfl_xor(ps, m);
        if (k == 0) arowp[js * BN + r0 + rr] = ps;
    }

    float x[TI], acc[TI];
#pragma unroll
    for (int r = 0; r < TI; ++r) {
        x[r] = ai[(size_t)(r0 + r) * Dc + d];
        acc[r] = 0.f;
    }
    __syncthreads();

    // ---- inner loop: NO barriers, all operands from LDS
    const int jbase = half * JH;
#pragma unroll 8
    for (int jj = 0; jj < JH; ++jj) {
        const float v = ajs[jbase + jj][d];
        const float4 a0 = *reinterpret_cast<const float4*>(&adjsT[jbase + jj][0]);
        const float4 a1 = *reinterpret_cast<const float4*>(&adjsT[jbase + jj][4]);
        const float4 a2 = *reinterpret_cast<const float4*>(&adjsT[jbase + jj][8]);
        const float4 a3 = *reinterpret_cast<const float4*>(&adjsT[jbase + jj][12]);
        acc[0]  = fmaf(a0.x, fmaxf(x[0]  + v, 0.f), acc[0]);
        acc[1]  = fmaf(a0.y, fmaxf(x[1]  + v, 0.f), acc[1]);
        acc[2]  = fmaf(a0.z, fmaxf(x[2]  + v, 0.f), acc[2]);
        acc[3]  = fmaf(a0.w, fmaxf(x[3]  + v, 0.f), acc[3]);
        acc[4]  = fmaf(a1.x, fmaxf(x[4]  + v, 0.f), acc[4]);
        acc[5]  = fmaf(a1.y, fmaxf(x[5]  + v, 0.f), acc[5]);
        acc[6]  = fmaf(a1.z, fmaxf(x[6]  + v, 0.f), acc[6]);
        acc[7]  = fmaf(a1.w, fmaxf(x[7]  + v, 0.f), acc[7]);
        acc[8]  = fmaf(a2.x, fmaxf(x[8]  + v, 0.f), acc[8]);
        acc[9]  = fmaf(a2.y, fmaxf(x[9]  + v, 0.f), acc[9]);
        acc[10] = fmaf(a2.z, fmaxf(x[10] + v, 0.f), acc[10]);
        acc[11] = fmaf(a2.w, fmaxf(x[11] + v, 0.f), acc[11]);
        acc[12] = fmaf(a3.x, fmaxf(x[12] + v, 0.f), acc[12]);
        acc[13] = fmaf(a3.y, fmaxf(x[13] + v, 0.f), acc[13]);
        acc[14] = fmaf(a3.z, fmaxf(x[14] + v, 0.f), acc[14]);
        acc[15] = fmaf(a3.w, fmaxf(x[15] + v, 0.f), acc[15]);
    }
    __syncthreads();

    // ---- combine halves, split the epilogue stores across halves.
    // half 0 parks acc[8..15] in slots 0..7; half 1 parks acc[0..7] in 8..15.
    float* xch = &ajs[0][0];
    if (half == 0) {
#pragma unroll
        for (int r = 0; r < 8; ++r) xch[r * Dc + d] = acc[8 + r];
    } else {
#pragma unroll
        for (int r = 0; r < 8; ++r) xch[(8 + r) * Dc + d] = acc[r];
    }
    __syncthreads();
    if (half == 0) {
#pragma unroll
        for (int r = 0; r < 8; ++r)
            sp[((size_t)js * BN + r0 + r) * Dc + d] = acc[r] + xch[(8 + r) * Dc + d];
    } else {
#pragma unroll
        for (int r = 0; r < 8; ++r)
            sp[((size_t)js * BN + r0 + 8 + r) * Dc + d] = acc[8 + r] + xch[r * Dc + d];
    }
}

// --- first linear (round-3 winner, verbatim)
__global__ __launch_bounds__(128) void gnn_lin1(const float* __restrict__ h,
                                                const float* __restrict__ wiT,
                                                const float* __restrict__ wjT,
                                                const float* __restrict__ b1,
                                                float* __restrict__ ai,
                                                float* __restrict__ aj) {
    __shared__ float hs[TN][Dc];
    const int o = threadIdx.x;
    const int r0 = blockIdx.x * TN;
#pragma unroll
    for (int t = 0; t < TN; ++t) hs[t][o] = h[(r0 + t) * Dc + o];
    __syncthreads();
    float acci[TN], accj[TN];
    const float bo = b1[o];
#pragma unroll
    for (int t = 0; t < TN; ++t) { acci[t] = bo; accj[t] = 0.f; }
    for (int d = 0; d < Dc; d += 4) {
        float wi[4], wj[4];
#pragma unroll
        for (int k = 0; k < 4; ++k) {
            wi[k] = wiT[(d + k) * Dc + o];
            wj[k] = wjT[(d + k) * Dc + o];
        }
#pragma unroll
        for (int t = 0; t < TN; ++t) {
            const float4 hv = *reinterpret_cast<const float4*>(&hs[t][d]);
            acci[t] = fmaf(hv.x, wi[0], acci[t]);
            acci[t] = fmaf(hv.y, wi[1], acci[t]);
            acci[t] = fmaf(hv.z, wi[2], acci[t]);
            acci[t] = fmaf(hv.w, wi[3], acci[t]);
            accj[t] = fmaf(hv.x, wj[0], accj[t]);
            accj[t] = fmaf(hv.y, wj[1], accj[t]);
            accj[t] = fmaf(hv.z, wj[2], accj[t]);
            accj[t] = fmaf(hv.w, wj[3], accj[t]);
        }
    }
#pragma unroll
    for (int t = 0; t < TN; ++t) {
        ai[(r0 + t) * Dc + o] = acci[t];
        aj[(r0 + t) * Dc + o] = accj[t];
    }
}

// --- final second linear + residual (sums JS partials)
__global__ __launch_bounds__(128) void gnn_lin2(const float* __restrict__ hin,
                                                const float* __restrict__ sp,
                                                const float* __restrict__ arowp,
                                                const float* __restrict__ w2T,
                                                const float* __restrict__ b2,
                                                float* __restrict__ hout) {
    __shared__ float ss[TN][Dc];
    const int o = threadIdx.x;
    const int r0 = blockIdx.x * TN;
#pragma unroll
    for (int t = 0; t < TN; ++t) {
        float v = 0.f;
#pragma unroll
        for (int js = 0; js < JS; ++js) v += sp[((size_t)js * BN + r0 + t) * Dc + o];
        ss[t][o] = v;
    }
    __syncthreads();
    float acc[TN];
#pragma unroll
    for (int t = 0; t < TN; ++t) acc[t] = 0.f;
    for (int d = 0; d < Dc; d += 4) {
        float w[4];
#pragma unroll
        for (int k = 0; k < 4; ++k) w[k] = w2T[(d + k) * Dc + o];
#pragma unroll
        for (int t = 0; t < TN; ++t) {
            const float4 sv = *reinterpret_cast<const float4*>(&ss[t][d]);
            acc[t] = fmaf(sv.x, w[0], acc[t]);
            acc[t] = fmaf(sv.y, w[1], acc[t]);
            acc[t] = fmaf(sv.z, w[2], acc[t]);
            acc[t] = fmaf(sv.w, w[3], acc[t]);
        }
    }
    const float b2o = b2[o];
#pragma unroll
    for (int t = 0; t < TN; ++t) {
        float ar = 0.f;
#pragma unroll
        for (int js = 0; js < JS; ++js) ar += arowp[js * BN + r0 + t];
        hout[(r0 + t) * Dc + o] = hin[(r0 + t) * Dc + o] + acc[t] + ar * b2o;
    }
}

// --- fused: lin2 of layer l (partials) + residual, then lin1 of layer l+1.
__global__ __launch_bounds__(128) void gnn_lin2lin1(const float* __restrict__ hin,
                                                    const float* __restrict__ sp,
                                                    const float* __restrict__ arowp,
                                                    const float* __restrict__ w2T,
                                                    const float* __restrict__ b2,
                                                    const float* __restrict__ wiT,
                                                    const float* __restrict__ wjT,
                                                    const float* __restrict__ b1,
                                                    float* __restrict__ hout,
                                                    float* __restrict__ ai,
                                                    float* __restrict__ aj) {
    __shared__ float ss[TN][Dc];
    const int o = threadIdx.x;
    const int r0 = blockIdx.x * TN;
#pragma unroll
    for (int t = 0; t < TN; ++t) {
        float v = 0.f;
#pragma unroll
        for (int js = 0; js < JS; ++js) v += sp[((size_t)js * BN + r0 + t) * Dc + o];
        ss[t][o] = v;
    }
    __syncthreads();
    float acc[TN];
#pragma unroll
    for (int t = 0; t < TN; ++t) acc[t] = 0.f;
    for (int d = 0; d < Dc; d += 4) {
        float w[4];
#pragma unroll
        for (int k = 0; k < 4; ++k) w[k] = w2T[(d + k) * Dc + o];
#pragma unroll
        for (int t = 0; t < TN; ++t) {
            const float4 sv = *reinterpret_cast<const float4*>(&ss[t][d]);
            acc[t] = fmaf(sv.x, w[0], acc[t]);
            acc[t] = fmaf(sv.y, w[1], acc[t]);
            acc[t] = fmaf(sv.z, w[2], acc[t]);
            acc[t] = fmaf(sv.w, w[3], acc[t]);
        }
    }
    const float b2o = b2[o];
    float hnew[TN];
#pragma unroll
    for (int t = 0; t < TN; ++t) {
        float ar = 0.f;
#pragma unroll
        for (int js = 0; js < JS; ++js) ar += arowp[js * BN + r0 + t];
        hnew[t] = hin[(r0 + t) * Dc + o] + acc[t] + ar * b2o;
        hout[(r0 + t) * Dc + o] = hnew[t];
    }
    __syncthreads();
#pragma unroll
    for (int t = 0; t < TN; ++t) ss[t][o] = hnew[t];
    __syncthreads();
    float acci[TN], accj[TN];
    const float bo = b1[o];
#pragma unroll
    for (int t = 0; t < TN; ++t) { acci[t] = bo; accj[t] = 0.f; }
    for (int d = 0; d < Dc; d += 4) {
        float wi[4], wj[4];
#pragma unroll
        for (int k = 0; k < 4; ++k) {
            wi[k] = wiT[(d + k) * Dc + o];
            wj[k] = wjT[(d + k) * Dc + o];
        }
#pragma unroll
        for (int t = 0; t < TN; ++t) {
            const float4 hv = *reinterpret_cast<const float4*>(&ss[t][d]);
            acci[t] = fmaf(hv.x, wi[0], acci[t]);
            acci[t] = fmaf(hv.y, wi[1], acci[t]);
            acci[t] = fmaf(hv.z, wi[2], acci[t]);
            acci[t] = fmaf(hv.w, wi[3], acci[t]);
            accj[t] = fmaf(hv.x, wj[0], accj[t]);
            accj[t] = fmaf(hv.y, wj[1], accj[t]);
            accj[t] = fmaf(hv.z, wj[2], accj[t]);
            accj[t] = fmaf(hv.w, wj[3], accj[t]);
        }
    }
#pragma unroll
    for (int t = 0; t < TN; ++t) {
        ai[(r0 + t) * Dc + o] = acci[t];
        aj[(r0 + t) * Dc + o] = accj[t];
    }
}

extern "C" void kernel_launch(void* const* d_in, const int* in_sizes, int n_in,
                              void* d_out, int out_size, void* d_ws, size_t ws_size,
                              hipStream_t stream) {
    const float* node = (const float*)d_in[0];
    const float* adj  = (const float*)d_in[1];
    const float* w1   = (const float*)d_in[2];
    const float* b1   = (const float*)d_in[3];
    const float* w2   = (const float*)d_in[4];
    const float* b2   = (const float*)d_in[5];
    float* out = (float*)d_out;

    float* ws = (float*)d_ws;
    float* wiT  = ws; ws += Lc * Dc * Dc;
    float* wjT  = ws; ws += Lc * Dc * Dc;
    float* w2T  = ws; ws += Lc * Dc * Dc;
    float* ai   = ws; ws += BN * Dc;
    float* aj   = ws; ws += BN * Dc;
    float* sp   = ws; ws += (size_t)JS * BN * Dc;
    float* arowp= ws; ws += JS * BN;
    float* h1   = ws; ws += BN * Dc;

    transpose_w_kernel<<<(Lc * Dc * Dc + 255) / 256, 256, 0, stream>>>(w1, w2, wiT, wjT, w2T);

    // layer 0
    gnn_lin1<<<BN / TN, 128, 0, stream>>>(node, wiT, wjT, b1, ai, aj);
    gnn_msg<<<(BN / TI) * JS, 256, 0, stream>>>(ai, aj, adj, sp, arowp);
    gnn_lin2lin1<<<BN / TN, 128, 0, stream>>>(node, sp, arowp, w2T, b2,
                                              wiT + Dc * Dc, wjT + Dc * Dc, b1 + Dc,
                                              h1, ai, aj);
    // layer 1
    gnn_msg<<<(BN / TI) * JS, 256, 0, stream>>>(ai, aj, adj, sp, arowp);
    gnn_lin2<<<BN / TN, 128, 0, stream>>>(h1, sp, arowp, w2T + Dc * Dc, b2 + Dc, out);
}